// Round 8
// baseline (337.563 us; speedup 1.0000x reference)
//
#include <hip/hip_runtime.h>
#include <hip/hip_bf16.h>

#define DI __device__ __forceinline__

typedef __attribute__((ext_vector_type(8))) short bf16x8;
typedef __attribute__((ext_vector_type(4))) float f32x4;
typedef __attribute__((ext_vector_type(4))) _Float16 f16x4;

constexpr int XPAD = 264;   // k2 A-tile row stride
constexpr float LOG2E = 1.4426950408889634f;

DI float fexp(float x) { return __builtin_amdgcn_exp2f(x * LOG2E); }  // raw v_exp_f32
DI float frcp(float x) { return __builtin_amdgcn_rcpf(x); }           // raw v_rcp_f32

DI short f2bf(float f) {                 // fp32 -> bf16 via HW cvt
  __hip_bfloat16 h = __float2bfloat16(f);
  union { __hip_bfloat16 h; short s; } c; c.h = h; return c.s;
}

DI unsigned pk2(float a, float b) {      // two f32 -> packed bf16x2 (HW cvt_pk)
  union { __hip_bfloat162 h; unsigned u; } c;
  c.h.x = __float2bfloat16(a); c.h.y = __float2bfloat16(b);
  return c.u;
}

DI short f2h(float f) {                  // fp32 -> f16 bits
  _Float16 h = (_Float16)f;
  union { _Float16 h; short s; } c; c.h = h; return c.s;
}

DI f16x4 pkh4(float a, float b, float c, float d) {   // 4 f32 -> f16x4 (cvt_pkrtz)
  auto lo = __builtin_amdgcn_cvt_pkrtz(a, b);         // __fp16 ext_vector(2)
  auto hi = __builtin_amdgcn_cvt_pkrtz(c, d);
  union { struct { decltype(lo) l, h; } p; f16x4 v; } u;
  u.p.l = lo; u.p.h = hi;
  return u.v;
}

DI f16x4 ld4h(const short* p) {          // 4 f16 (8 B)
  union { uint2 u; f16x4 v; } c;
  c.u = *(const uint2*)p;
  return c.v;
}

DI f32x4 mfma16(bf16x8 a, bf16x8 b, f32x4 c) {
  // A: row=l&15, k=(l>>4)*8+j ; B: col=l&15, k=(l>>4)*8+j ; D: col=l&15, row=(l>>4)*4+reg
  return __builtin_amdgcn_mfma_f32_16x16x32_bf16(a, b, c, 0, 0, 0);
}

DI f32x4 mfmah(f16x4 a, f16x4 b, f32x4 c) {
  // 16x16x16 f16: A row=l&15, k=(l>>4)*4+j ; B col=l&15, k=(l>>4)*4+j ; D as above.
  // A/B fragment layout == D layout of the 16x16 family -> GEMM accumulators
  // convert to next-MFMA operands with an own-lane pack (no shfl, no LDS).
  return __builtin_amdgcn_mfma_f32_16x16x16f16(a, b, c, 0, 0, 0);
}

DI f32x4 fzero() { return f32x4{0.f, 0.f, 0.f, 0.f}; }

// Xs swizzled element index: row-major [64][256] bf16, XOR bits 3..5 of the
// element offset with row&7 -> b128 reads across rows hit all 32 banks.
DI int xsw(int row, int e) { return row * 256 + (e ^ ((row & 7) << 3)); }

// ---------------- K0: weights fp32 -> bf16 into ws (Wq pre-scaled) ----------------
__global__ void wconv_kernel(const float* __restrict__ a, const float* __restrict__ b,
                             const float* __restrict__ c, const float* __restrict__ d,
                             short* __restrict__ o) {
  int i = blockIdx.x * 256 + threadIdx.x;
  int mat = i >> 14;                         // block-uniform
  int off = (i & 16383) * 4;
  const float* s = (mat == 0) ? a : (mat == 1) ? b : (mat == 2) ? c : d;
  const float sc = (mat == 0) ? 0.125f : 1.0f;   // fold Ch^-0.5 into Wq
  float4 v = *(const float4*)(s + off);
  uint2 r; r.x = pk2(v.x * sc, v.y * sc); r.y = pk2(v.z * sc, v.w * sc);
  *(uint2*)(o + mat * 65536 + off) = r;
}

// ---------------- K0x: x -> bf16, transposed into k1's EXACT swizzled Xs order ----
__global__ __launch_bounds__(256, 2)
void xt_kernel(const float* __restrict__ x, short* __restrict__ xt, int n0chunk) {
  __shared__ short T[64 * 258];       // [px][c], stride 258 breaks bank aliasing
  const int tid = threadIdx.x;
  const int gi  = blockIdx.x >> 4;    // 64-px group within chunk
  const int t   = blockIdx.x & 15;
  const int n0g = n0chunk + gi * 64;  // global pixel base (64-aligned)
  const int b   = n0g >> 12;
  const int hw0 = n0g & 4095;
  const float* xb = x + ((size_t)(b * 16 + t) * 256) * 4096 + hw0;

  // read phase: 256 B coalesced segments along px; scalar bf16 scatter into T
  #pragma unroll
  for (int ci = 0; ci < 16; ++ci) {
    const int c   = ci * 16 + (tid >> 4);
    const int px4 = tid & 15;
    float4 v = *(const float4*)(xb + (size_t)c * 4096 + px4 * 4);
    T[(px4 * 4 + 0) * 258 + c] = f2bf(v.x);
    T[(px4 * 4 + 1) * 258 + c] = f2bf(v.y);
    T[(px4 * 4 + 2) * 258 + c] = f2bf(v.z);
    T[(px4 * 4 + 3) * 258 + c] = f2bf(v.w);
  }
  __syncthreads();

  // write phase: wave w writes pixel px = it*4+w, full 512 B row, swizzled
  const int wave = tid >> 6, lane = tid & 63;
  #pragma unroll
  for (int itp = 0; itp < 16; ++itp) {
    const int px  = itp * 4 + wave;
    const int row = (px & 3) * 16 + t;
    const int sw8 = (row & 7) << 3;
    const size_t obase = ((size_t)(gi * 16 + (px >> 2))) * 16384 + row * 256;
    const int dstc = (((lane >> 1) * 8) ^ sw8) + (lane & 1) * 4;
    const int tb = px * 258 + lane * 4;
    union { short s[4]; uint2 u; } pk;
    pk.s[0] = T[tb + 0]; pk.s[1] = T[tb + 1];
    pk.s[2] = T[tb + 2]; pk.s[3] = T[tb + 3];
    *(uint2*)&xt[obase + dstc] = pk.u;
  }
}

// ---------------- K1: fused QKV + softmaxes + linear attention ----------------
// One WG = 4 consecutive pixels, 256 threads (4 waves). Each wave = one head.
// STRUCTURE C (round-7 post-mortem): round 7's qsg global round-trip + the
// (256,4) cap produced ~50 MB of spill traffic (FETCH/WRITE residue) and a
// mid-kernel vmcnt(0) drain.  Fix: K pass -> V pass (akf/bvf as before), then
// PER PIXEL: {Q-GEMM for that pixel only (qacc[4] = 16 regs), softmax -> 2 KB
// per-wave LDS qs (round-6's proven swizzled code), register-kv, out}.
// Peak liveness ~110 (akf 32 + bvf 32 + qacc 16 + temps) fits the (256,4)
// 128-reg unified cap with margin -> no spill, no global q_soft, no drain.
// Cost: Q-weights re-read 4x per wave (L2-resident, latency-hidden).
// LDS 40960 (Xs 32 KB + qs 8 KB) -> still 4 blocks/CU.
__global__ __launch_bounds__(256, 4)
void k1_kernel(const short* __restrict__ xt, const short* __restrict__ wbf,
               short* __restrict__ att) {
  __shared__ short SMEM[20480];       // 40960 B: Xs 32 KB + qs 8 KB
  short* Xs = SMEM;

  const int tid  = threadIdx.x;
  const int wave = tid >> 6;          // = head
  const int lane = tid & 63;
  const int g    = lane >> 4;
  const int li   = lane & 15;

  short* qs = SMEM + 16384 + wave * 1024;   // 16 t x 64 c f16, reused per px

  // XCD-aware swizzle: consecutive logical bids (adjacent pixels) on same XCD
  int bid = blockIdx.x;
  const int nb = gridDim.x;
  if ((nb & 7) == 0) { const int q = nb >> 3; bid = (bid & 7) * q + (bid >> 3); }

  // ---- Phase 0: async linear copy of the pre-swizzled 32 KB tile ----
  {
    const short* src = xt + (size_t)bid * 16384 + wave * 512 + lane * 8;
    #pragma unroll
    for (int it = 0; it < 8; ++it) {
      __builtin_amdgcn_global_load_lds(
          (const __attribute__((address_space(1))) void*)(src + it * 2048),
          (__attribute__((address_space(3))) void*)(SMEM + it * 2048 + wave * 512),
          16, 0, 0);
    }
  }
  __syncthreads();   // the ONLY barrier (drains vmcnt incl. global_load_lds)

  const short* wq = wbf;
  const short* wk = wbf + 65536;
  const short* wv = wbf + 131072;
  const size_t wrow = (size_t)(wave * 64) * 256;

  // ---- Pass K (all 4 px) -> t-softmax -> own-lane f16 A-frags ----
  f16x4 akf[4][4];
  {
    f32x4 kacc[4][4];
    #pragma unroll
    for (int p = 0; p < 4; ++p)
      #pragma unroll
      for (int nt = 0; nt < 4; ++nt) kacc[p][nt] = fzero();

    __builtin_amdgcn_s_setprio(1);
    #pragma unroll
    for (int ks = 0; ks < 8; ++ks) {
      bf16x8 kb[4];
      #pragma unroll
      for (int nt = 0; nt < 4; ++nt)
        kb[nt] = *(const bf16x8*)(wk + wrow + (size_t)(nt * 16 + li) * 256 + ks * 32 + g * 8);
      #pragma unroll
      for (int p = 0; p < 4; ++p) {
        bf16x8 af = *(const bf16x8*)&Xs[xsw(p * 16 + li, ks * 32 + g * 8)];
        #pragma unroll
        for (int nt = 0; nt < 4; ++nt)
          kacc[p][nt] = mfma16(af, kb[nt], kacc[p][nt]);
      }
    }
    __builtin_amdgcn_s_setprio(0);

    // softmax over t (4 regs + g-groups), no max-sub (scores ~ N(0,1))
    #pragma unroll
    for (int p = 0; p < 4; ++p)
      #pragma unroll
      for (int nt = 0; nt < 4; ++nt) {
        float e0 = fexp(kacc[p][nt][0]);
        float e1 = fexp(kacc[p][nt][1]);
        float e2 = fexp(kacc[p][nt][2]);
        float e3 = fexp(kacc[p][nt][3]);
        float s = e0 + e1 + e2 + e3;
        s += __shfl_xor(s, 16);
        s += __shfl_xor(s, 32);
        const float inv = frcp(s);
        akf[p][nt] = pkh4(e0 * inv, e1 * inv, e2 * inv, e3 * inv);
      }
  }

  // ---- Pass V (two nt-halves; vacc[4][2] live) -> own-lane f16 B-frags ----
  f16x4 bvf[4][4];
  #pragma unroll
  for (int h = 0; h < 2; ++h) {
    f32x4 vacc[4][2];
    #pragma unroll
    for (int p = 0; p < 4; ++p)
      #pragma unroll
      for (int n2 = 0; n2 < 2; ++n2) vacc[p][n2] = fzero();

    __builtin_amdgcn_s_setprio(1);
    #pragma unroll
    for (int ks = 0; ks < 8; ++ks) {
      bf16x8 vb[2];
      #pragma unroll
      for (int n2 = 0; n2 < 2; ++n2)
        vb[n2] = *(const bf16x8*)(wv + wrow + (size_t)((h * 2 + n2) * 16 + li) * 256 + ks * 32 + g * 8);
      #pragma unroll
      for (int p = 0; p < 4; ++p) {
        bf16x8 af = *(const bf16x8*)&Xs[xsw(p * 16 + li, ks * 32 + g * 8)];
        #pragma unroll
        for (int n2 = 0; n2 < 2; ++n2)
          vacc[p][n2] = mfma16(af, vb[n2], vacc[p][n2]);
      }
    }
    __builtin_amdgcn_s_setprio(0);

    #pragma unroll
    for (int p = 0; p < 4; ++p)
      #pragma unroll
      for (int n2 = 0; n2 < 2; ++n2)
        bvf[p][h * 2 + n2] = pkh4(vacc[p][n2][0], vacc[p][n2][1],
                                  vacc[p][n2][2], vacc[p][n2][3]);
  }

  // ---- Per-pixel: Q-GEMM + softmax -> qs LDS; kv pure-register; out ----
  #pragma unroll
  for (int p = 0; p < 4; ++p) {
    // Q-GEMM for this pixel only (qacc[4] = 16 regs; scale pre-folded in wq)
    f32x4 qacc[4];
    #pragma unroll
    for (int nt = 0; nt < 4; ++nt) qacc[nt] = fzero();

    __builtin_amdgcn_s_setprio(1);
    #pragma unroll
    for (int ks = 0; ks < 8; ++ks) {
      bf16x8 qb[4];
      #pragma unroll
      for (int nt = 0; nt < 4; ++nt)
        qb[nt] = *(const bf16x8*)(wq + wrow + (size_t)(nt * 16 + li) * 256 + ks * 32 + g * 8);
      bf16x8 af = *(const bf16x8*)&Xs[xsw(p * 16 + li, ks * 32 + g * 8)];
      #pragma unroll
      for (int nt = 0; nt < 4; ++nt)
        qacc[nt] = mfma16(af, qb[nt], qacc[nt]);
    }
    __builtin_amdgcn_s_setprio(0);

    // Q softmax over c (64 per head), no max-sub -> qs (f16 LDS, swizzled)
    #pragma unroll
    for (int r = 0; r < 4; ++r) {
      float e0 = fexp(qacc[0][r]);
      float e1 = fexp(qacc[1][r]);
      float e2 = fexp(qacc[2][r]);
      float e3 = fexp(qacc[3][r]);
      float s = e0 + e1 + e2 + e3;
      s += __shfl_xor(s, 1); s += __shfl_xor(s, 2);
      s += __shfl_xor(s, 4); s += __shfl_xor(s, 8);
      const float inv = frcp(s);
      const int t = g * 4 + r;
      const int xw = (t & 7) << 3;          // 8-granule row swizzle
      short* dq = qs + t * 64;
      dq[( 0 + li) ^ xw] = f2h(e0 * inv);
      dq[(16 + li) ^ xw] = f2h(e1 * inv);
      dq[(32 + li) ^ xw] = f2h(e2 * inv);
      dq[(48 + li) ^ xw] = f2h(e3 * inv);
    }

    // kv (16x16x16 f16) pure-register; out = q_soft @ kv
    f32x4 oacc[4];
    #pragma unroll
    for (int nt = 0; nt < 4; ++nt) oacc[nt] = fzero();

    #pragma unroll
    for (int cq = 0; cq < 4; ++cq) {        // c-chunks of 16
      // kv chunk: kva[nt] lane holds kv[c=cq*16+g*4+r][d=nt*16+li]
      f32x4 kva[4];
      #pragma unroll
      for (int nt = 0; nt < 4; ++nt)
        kva[nt] = mfmah(akf[p][cq], bvf[p][nt], fzero());
      // aq: A-frag q_soft[t=li][c=cq*16+g*4+j] from qs (same-wave LDS)
      f16x4 aq = ld4h(qs + li * 64 + (((cq * 16 + g * 4) ^ ((li & 7) << 3))));
      // kva IS the mfmah B-frag (k=g*4+j, n=li) -> own-lane pack, no transpose
      #pragma unroll
      for (int nt = 0; nt < 4; ++nt) {
        f16x4 kb16 = pkh4(kva[nt][0], kva[nt][1], kva[nt][2], kva[nt][3]);
        oacc[nt] = mfmah(aq, kb16, oacc[nt]);
      }
    }

    const size_t arow = ((size_t)bid * 4 + p) * 16;
    #pragma unroll
    for (int nt = 0; nt < 4; ++nt)
      #pragma unroll
      for (int r = 0; r < 4; ++r)
        att[(arow + g * 4 + r) * 256 + wave * 64 + nt * 16 + li] = f2bf(oacc[nt][r]);
  }
}

// ---------------- K2: out = attn @ Wp^T, transposed coalesced store ----------------
__global__ __launch_bounds__(256, 2)
void k2_kernel(const short* __restrict__ att, const short* __restrict__ wpb,
               float* __restrict__ out, int n0chunk) {
  __shared__ short A[128 * XPAD];
  const int tid = threadIdx.x;
  const int wave = tid >> 6, lane = tid & 63, g = lane >> 4, li = lane & 15;
  const int pb = blockIdx.x >> 1;
  const int t0 = (blockIdx.x & 1) * 8;
  const int n0 = n0chunk + pb * 16;
  const int b = n0 >> 12, hw0 = n0 & 4095;

  for (int idx = tid; idx < 128 * 32; idx += 256) {
    const int row = idx >> 5, seg = idx & 31;
    const int p = row & 15, tl = row >> 4;
    const short* src = att + ((size_t)((pb * 16 + p) * 16 + t0 + tl)) * 256 + seg * 8;
    *(int4*)&A[row * XPAD + seg * 8] = *(const int4*)src;
  }
  __syncthreads();

  f32x4 acc[8][4];
  #pragma unroll
  for (int mt = 0; mt < 8; ++mt)
    #pragma unroll
    for (int n4 = 0; n4 < 4; ++n4) acc[mt][n4] = fzero();

  #pragma unroll
  for (int ks = 0; ks < 8; ++ks) {
    bf16x8 bf[4];
    #pragma unroll
    for (int n4 = 0; n4 < 4; ++n4)
      bf[n4] = *(const bf16x8*)(wpb + (size_t)((wave * 4 + n4) * 16 + li) * 256 + ks * 32 + g * 8);
    #pragma unroll
    for (int mt = 0; mt < 8; ++mt) {
      bf16x8 af = *(const bf16x8*)&A[(mt * 16 + li) * XPAD + ks * 32 + g * 8];
      #pragma unroll
      for (int n4 = 0; n4 < 4; ++n4) acc[mt][n4] = mfma16(af, bf[n4], acc[mt][n4]);
    }
  }

  float* ob = out + (size_t)b * (16 * 256 * 4096) + hw0;
  #pragma unroll
  for (int mt = 0; mt < 8; ++mt)
    #pragma unroll
    for (int n4 = 0; n4 < 4; ++n4) {
      const int t = t0 + mt;
      const int c = (wave * 4 + n4) * 16 + li;
      float4 v;
      v.x = acc[mt][n4][0]; v.y = acc[mt][n4][1];
      v.z = acc[mt][n4][2]; v.w = acc[mt][n4][3];
      *(float4*)(ob + (size_t)(t * 256 + c) * 4096 + g * 4) = v;
    }
}

extern "C" void kernel_launch(void* const* d_in, const int* in_sizes, int n_in,
                              void* d_out, int out_size, void* d_ws, size_t ws_size,
                              hipStream_t stream) {
  const float* x  = (const float*)d_in[0];
  const float* Wq = (const float*)d_in[1];
  const float* Wk = (const float*)d_in[2];
  const float* Wv = (const float*)d_in[3];
  const float* Wp = (const float*)d_in[4];
  float* out = (float*)d_out;

  short* wbf = (short*)d_ws;          // 4 x 65536 bf16 = 512 KB
  short* att = wbf + 4 * 65536;       // attn scratch (bf16), chunked

  wconv_kernel<<<256, 256, 0, stream>>>(Wq, Wk, Wv, Wp, wbf);

  const size_t wsAvail = (ws_size > 524288) ? (ws_size - 524288) : 0;
  const size_t perPix = 16 * 256 * 2;  // 8 KB per pixel each for att, xt
  int chunk = 64;                      // xt tiles need 64-px groups
  while (chunk < 8192 && (size_t)(chunk * 2) * perPix <= wsAvail) chunk <<= 1;

  short* xtb = att + (size_t)chunk * 4096;   // transposed-x scratch: chunk x 8 KB

  for (int n0 = 0; n0 < 8192; n0 += chunk) {
    xt_kernel<<<(chunk / 64) * 16, 256, 0, stream>>>(x, xtb, n0);
    k1_kernel<<<chunk / 4, 256, 0, stream>>>(xtb, wbf, att);
    k2_kernel<<<(chunk / 16) * 2, 256, 0, stream>>>(att, wbf + 3 * 65536, out, n0);
  }
}

// Round 9
// 326.013 us; speedup vs baseline: 1.0354x; 1.0354x over previous
//
#include <hip/hip_runtime.h>
#include <hip/hip_bf16.h>

#define DI __device__ __forceinline__

typedef __attribute__((ext_vector_type(8))) short bf16x8;
typedef __attribute__((ext_vector_type(4))) float f32x4;
typedef __attribute__((ext_vector_type(4))) _Float16 f16x4;

constexpr int XPAD = 264;   // k2 A-tile row stride
constexpr float LOG2E = 1.4426950408889634f;

DI float fexp(float x) { return __builtin_amdgcn_exp2f(x * LOG2E); }  // raw v_exp_f32
DI float frcp(float x) { return __builtin_amdgcn_rcpf(x); }           // raw v_rcp_f32

DI short f2bf(float f) {                 // fp32 -> bf16 via HW cvt
  __hip_bfloat16 h = __float2bfloat16(f);
  union { __hip_bfloat16 h; short s; } c; c.h = h; return c.s;
}

DI unsigned pk2(float a, float b) {      // two f32 -> packed bf16x2 (HW cvt_pk)
  union { __hip_bfloat162 h; unsigned u; } c;
  c.h.x = __float2bfloat16(a); c.h.y = __float2bfloat16(b);
  return c.u;
}

DI short f2h(float f) {                  // fp32 -> f16 bits
  _Float16 h = (_Float16)f;
  union { _Float16 h; short s; } c; c.h = h; return c.s;
}

DI f16x4 pkh4(float a, float b, float c, float d) {   // 4 f32 -> f16x4 (cvt_pkrtz)
  auto lo = __builtin_amdgcn_cvt_pkrtz(a, b);         // __fp16 ext_vector(2)
  auto hi = __builtin_amdgcn_cvt_pkrtz(c, d);
  union { struct { decltype(lo) l, h; } p; f16x4 v; } u;
  u.p.l = lo; u.p.h = hi;
  return u.v;
}

DI f16x4 ld4h(const short* p) {          // 4 f16 (8 B)
  union { uint2 u; f16x4 v; } c;
  c.u = *(const uint2*)p;
  return c.v;
}

DI f32x4 mfma16(bf16x8 a, bf16x8 b, f32x4 c) {
  // A: row=l&15, k=(l>>4)*8+j ; B: col=l&15, k=(l>>4)*8+j ; D: col=l&15, row=(l>>4)*4+reg
  return __builtin_amdgcn_mfma_f32_16x16x32_bf16(a, b, c, 0, 0, 0);
}

DI f32x4 mfmah(f16x4 a, f16x4 b, f32x4 c) {
  // 16x16x16 f16: A row=l&15, k=(l>>4)*4+j ; B col=l&15, k=(l>>4)*4+j ; D as above.
  // A/B fragment layout == D layout of the 16x16 family -> GEMM accumulators
  // convert to next-MFMA operands with an own-lane pack (no shfl, no LDS).
  return __builtin_amdgcn_mfma_f32_16x16x16f16(a, b, c, 0, 0, 0);
}

DI f32x4 fzero() { return f32x4{0.f, 0.f, 0.f, 0.f}; }

// Xs swizzled element index: row-major [64][256] bf16, XOR bits 3..5 of the
// element offset with row&7 -> b128 reads across rows hit all 32 banks.
DI int xsw(int row, int e) { return row * 256 + (e ^ ((row & 7) << 3)); }

// ---------------- K0: weights fp32 -> bf16 into ws (Wq pre-scaled) ----------------
__global__ void wconv_kernel(const float* __restrict__ a, const float* __restrict__ b,
                             const float* __restrict__ c, const float* __restrict__ d,
                             short* __restrict__ o) {
  int i = blockIdx.x * 256 + threadIdx.x;
  int mat = i >> 14;                         // block-uniform
  int off = (i & 16383) * 4;
  const float* s = (mat == 0) ? a : (mat == 1) ? b : (mat == 2) ? c : d;
  const float sc = (mat == 0) ? 0.125f : 1.0f;   // fold Ch^-0.5 into Wq
  float4 v = *(const float4*)(s + off);
  uint2 r; r.x = pk2(v.x * sc, v.y * sc); r.y = pk2(v.z * sc, v.w * sc);
  *(uint2*)(o + mat * 65536 + off) = r;
}

// ---------------- K0x: x -> bf16, transposed into k1's EXACT swizzled Xs order ----
__global__ __launch_bounds__(256, 2)
void xt_kernel(const float* __restrict__ x, short* __restrict__ xt, int n0chunk) {
  __shared__ short T[64 * 258];       // [px][c], stride 258 breaks bank aliasing
  const int tid = threadIdx.x;
  const int gi  = blockIdx.x >> 4;    // 64-px group within chunk
  const int t   = blockIdx.x & 15;
  const int n0g = n0chunk + gi * 64;  // global pixel base (64-aligned)
  const int b   = n0g >> 12;
  const int hw0 = n0g & 4095;
  const float* xb = x + ((size_t)(b * 16 + t) * 256) * 4096 + hw0;

  // read phase: 256 B coalesced segments along px; scalar bf16 scatter into T
  #pragma unroll
  for (int ci = 0; ci < 16; ++ci) {
    const int c   = ci * 16 + (tid >> 4);
    const int px4 = tid & 15;
    float4 v = *(const float4*)(xb + (size_t)c * 4096 + px4 * 4);
    T[(px4 * 4 + 0) * 258 + c] = f2bf(v.x);
    T[(px4 * 4 + 1) * 258 + c] = f2bf(v.y);
    T[(px4 * 4 + 2) * 258 + c] = f2bf(v.z);
    T[(px4 * 4 + 3) * 258 + c] = f2bf(v.w);
  }
  __syncthreads();

  // write phase: wave w writes pixel px = it*4+w, full 512 B row, swizzled
  const int wave = tid >> 6, lane = tid & 63;
  #pragma unroll
  for (int itp = 0; itp < 16; ++itp) {
    const int px  = itp * 4 + wave;
    const int row = (px & 3) * 16 + t;
    const int sw8 = (row & 7) << 3;
    const size_t obase = ((size_t)(gi * 16 + (px >> 2))) * 16384 + row * 256;
    const int dstc = (((lane >> 1) * 8) ^ sw8) + (lane & 1) * 4;
    const int tb = px * 258 + lane * 4;
    union { short s[4]; uint2 u; } pk;
    pk.s[0] = T[tb + 0]; pk.s[1] = T[tb + 1];
    pk.s[2] = T[tb + 2]; pk.s[3] = T[tb + 3];
    *(uint2*)&xt[obase + dstc] = pk.u;
  }
}

// ---------------- K1: fused QKV + softmaxes + linear attention ----------------
// STRUCTURE D (round-8 post-mortem): r7's pass discipline (Q-first -> qsg,
// per-pass accumulators die into 16-reg f16 frags, no cross-pass GEMM liveness)
// was the only spill-free 4w/SIMD config, but its waves are latency-exposed
// (both pipes <20% at 43% occupancy).  Here: SAME passes, 512 threads, 8 waves
// = (head h, px-pair s); each wave owns 2 pixels.  All accumulator arrays
// halve (qacc/kacc/vacc[2][4]) -> peak liveness ~70-80 regs -> expect
// VGPR <= 80 (maybe <= 64 -> 6-8 waves/SIMD latency hiding).  Weight L2
// traffic doubles (768 KB/block) -- the diagnostic: occupancy up + dur flat
// means weight-L2-bound -> next step stages weights via LDS.
__global__ __launch_bounds__(512, 4)
void k1_kernel(const short* __restrict__ xt, const short* __restrict__ wbf,
               short* __restrict__ att, short* __restrict__ qsg) {
  __shared__ short SMEM[16384];       // 32768 B: Xs only
  short* Xs = SMEM;

  const int tid  = threadIdx.x;
  const int wv   = tid >> 6;          // 0..7
  const int lane = tid & 63;
  const int g    = lane >> 4;
  const int li   = lane & 15;
  const int h    = wv & 3;            // head
  const int s    = wv >> 2;           // px-pair selector: px = 2s, 2s+1

  // XCD-aware swizzle: consecutive logical bids (adjacent pixels) on same XCD
  int bid = blockIdx.x;
  const int nb = gridDim.x;
  if ((nb & 7) == 0) { const int q = nb >> 3; bid = (bid & 7) * q + (bid >> 3); }

  // ---- Phase 0: async linear copy of the pre-swizzled 32 KB tile ----
  // 512 thr x 16 B = 8 KB per round; 4 rounds.  Wave segment: 1 KB per round.
  {
    const short* src = xt + (size_t)bid * 16384 + wv * 512 + lane * 8;
    #pragma unroll
    for (int it = 0; it < 4; ++it) {
      __builtin_amdgcn_global_load_lds(
          (const __attribute__((address_space(1))) void*)(src + it * 4096),
          (__attribute__((address_space(3))) void*)(SMEM + it * 4096 + wv * 512),
          16, 0, 0);
    }
  }
  __syncthreads();   // the ONLY barrier (drains vmcnt incl. global_load_lds)

  const short* wq = wbf;
  const short* wk = wbf + 65536;
  const short* wv_ = wbf + 131072;
  const size_t wrow = (size_t)(h * 64) * 256;

  // ---- Pass Q FIRST (2 px; scale pre-folded into wq) ----
  {
    f32x4 qacc[2][4];
    #pragma unroll
    for (int p = 0; p < 2; ++p)
      #pragma unroll
      for (int nt = 0; nt < 4; ++nt) qacc[p][nt] = fzero();

    __builtin_amdgcn_s_setprio(1);
    #pragma unroll
    for (int ks = 0; ks < 8; ++ks) {
      bf16x8 qb[4];
      #pragma unroll
      for (int nt = 0; nt < 4; ++nt)
        qb[nt] = *(const bf16x8*)(wq + wrow + (size_t)(nt * 16 + li) * 256 + ks * 32 + g * 8);
      #pragma unroll
      for (int p = 0; p < 2; ++p) {
        bf16x8 af = *(const bf16x8*)&Xs[xsw((2 * s + p) * 16 + li, ks * 32 + g * 8)];
        #pragma unroll
        for (int nt = 0; nt < 4; ++nt)
          qacc[p][nt] = mfma16(af, qb[nt], qacc[p][nt]);
      }
    }
    __builtin_amdgcn_s_setprio(0);

    // Q softmax over c (64 per head), no max-sub -> normalized f16 to qsg
    #pragma unroll
    for (int p = 0; p < 2; ++p) {
      short* qsp = qsg + ((size_t)(bid * 4 + 2 * s + p) * 4 + h) * 1024;
      #pragma unroll
      for (int r = 0; r < 4; ++r) {
        float e0 = fexp(qacc[p][0][r]);
        float e1 = fexp(qacc[p][1][r]);
        float e2 = fexp(qacc[p][2][r]);
        float e3 = fexp(qacc[p][3][r]);
        float sm = e0 + e1 + e2 + e3;
        sm += __shfl_xor(sm, 1); sm += __shfl_xor(sm, 2);
        sm += __shfl_xor(sm, 4); sm += __shfl_xor(sm, 8);
        const float inv = frcp(sm);
        const int t = g * 4 + r;
        short* dst = qsp + t * 64 + li;
        dst[0]  = f2h(e0 * inv);
        dst[16] = f2h(e1 * inv);
        dst[32] = f2h(e2 * inv);
        dst[48] = f2h(e3 * inv);
      }
    }
  }

  // ---- Pass K (2 px) -> t-softmax -> own-lane f16 A-frags ----
  f16x4 akf[2][4];
  {
    f32x4 kacc[2][4];
    #pragma unroll
    for (int p = 0; p < 2; ++p)
      #pragma unroll
      for (int nt = 0; nt < 4; ++nt) kacc[p][nt] = fzero();

    __builtin_amdgcn_s_setprio(1);
    #pragma unroll
    for (int ks = 0; ks < 8; ++ks) {
      bf16x8 kb[4];
      #pragma unroll
      for (int nt = 0; nt < 4; ++nt)
        kb[nt] = *(const bf16x8*)(wk + wrow + (size_t)(nt * 16 + li) * 256 + ks * 32 + g * 8);
      #pragma unroll
      for (int p = 0; p < 2; ++p) {
        bf16x8 af = *(const bf16x8*)&Xs[xsw((2 * s + p) * 16 + li, ks * 32 + g * 8)];
        #pragma unroll
        for (int nt = 0; nt < 4; ++nt)
          kacc[p][nt] = mfma16(af, kb[nt], kacc[p][nt]);
      }
    }
    __builtin_amdgcn_s_setprio(0);

    // softmax over t (4 regs + g-groups), no max-sub (scores ~ N(0,1))
    #pragma unroll
    for (int p = 0; p < 2; ++p)
      #pragma unroll
      for (int nt = 0; nt < 4; ++nt) {
        float e0 = fexp(kacc[p][nt][0]);
        float e1 = fexp(kacc[p][nt][1]);
        float e2 = fexp(kacc[p][nt][2]);
        float e3 = fexp(kacc[p][nt][3]);
        float sm = e0 + e1 + e2 + e3;
        sm += __shfl_xor(sm, 16);
        sm += __shfl_xor(sm, 32);
        const float inv = frcp(sm);
        akf[p][nt] = pkh4(e0 * inv, e1 * inv, e2 * inv, e3 * inv);
      }
  }

  // ---- Pass V (2 px, full nt; vacc[2][4] = 32 regs) -> own-lane f16 B-frags ----
  f16x4 bvf[2][4];
  {
    f32x4 vacc[2][4];
    #pragma unroll
    for (int p = 0; p < 2; ++p)
      #pragma unroll
      for (int nt = 0; nt < 4; ++nt) vacc[p][nt] = fzero();

    __builtin_amdgcn_s_setprio(1);
    #pragma unroll
    for (int ks = 0; ks < 8; ++ks) {
      bf16x8 vb[4];
      #pragma unroll
      for (int nt = 0; nt < 4; ++nt)
        vb[nt] = *(const bf16x8*)(wv_ + wrow + (size_t)(nt * 16 + li) * 256 + ks * 32 + g * 8);
      #pragma unroll
      for (int p = 0; p < 2; ++p) {
        bf16x8 af = *(const bf16x8*)&Xs[xsw((2 * s + p) * 16 + li, ks * 32 + g * 8)];
        #pragma unroll
        for (int nt = 0; nt < 4; ++nt)
          vacc[p][nt] = mfma16(af, vb[nt], vacc[p][nt]);
      }
    }
    __builtin_amdgcn_s_setprio(0);

    #pragma unroll
    for (int p = 0; p < 2; ++p)
      #pragma unroll
      for (int nt = 0; nt < 4; ++nt)
        bvf[p][nt] = pkh4(vacc[p][nt][0], vacc[p][nt][1],
                          vacc[p][nt][2], vacc[p][nt][3]);
  }

  // ensure this wave's qsg stores are retired before reading them back
  asm volatile("s_waitcnt vmcnt(0)" ::: "memory");

  // ---- Per-pixel stage B: kv (16x16x16 f16) pure-register; out; att store ----
  #pragma unroll
  for (int p = 0; p < 2; ++p) {
    const short* qsp = qsg + ((size_t)(bid * 4 + 2 * s + p) * 4 + h) * 1024;
    f32x4 oacc[4];
    #pragma unroll
    for (int nt = 0; nt < 4; ++nt) oacc[nt] = fzero();

    #pragma unroll
    for (int cq = 0; cq < 4; ++cq) {        // c-chunks of 16
      // kv chunk: kva[nt] lane holds kv[c=cq*16+g*4+r][d=nt*16+li]
      f32x4 kva[4];
      #pragma unroll
      for (int nt = 0; nt < 4; ++nt)
        kva[nt] = mfmah(akf[p][cq], bvf[p][nt], fzero());
      // aq: A-frag q_soft[t=li][c=cq*16+g*4+j] from qsg (L2-hot)
      f16x4 aq = ld4h(qsp + li * 64 + cq * 16 + g * 4);
      // kva IS the mfmah B-frag (k=g*4+j, n=li) -> own-lane pack, no transpose
      #pragma unroll
      for (int nt = 0; nt < 4; ++nt) {
        f16x4 kb16 = pkh4(kva[nt][0], kva[nt][1], kva[nt][2], kva[nt][3]);
        oacc[nt] = mfmah(aq, kb16, oacc[nt]);
      }
    }

    const size_t arow = ((size_t)bid * 4 + 2 * s + p) * 16;
    #pragma unroll
    for (int nt = 0; nt < 4; ++nt)
      #pragma unroll
      for (int r = 0; r < 4; ++r)
        att[(arow + g * 4 + r) * 256 + h * 64 + nt * 16 + li] = f2bf(oacc[nt][r]);
  }
}

// ---------------- K2: out = attn @ Wp^T, transposed coalesced store ----------------
__global__ __launch_bounds__(256, 2)
void k2_kernel(const short* __restrict__ att, const short* __restrict__ wpb,
               float* __restrict__ out, int n0chunk) {
  __shared__ short A[128 * XPAD];
  const int tid = threadIdx.x;
  const int wave = tid >> 6, lane = tid & 63, g = lane >> 4, li = lane & 15;
  const int pb = blockIdx.x >> 1;
  const int t0 = (blockIdx.x & 1) * 8;
  const int n0 = n0chunk + pb * 16;
  const int b = n0 >> 12, hw0 = n0 & 4095;

  for (int idx = tid; idx < 128 * 32; idx += 256) {
    const int row = idx >> 5, seg = idx & 31;
    const int p = row & 15, tl = row >> 4;
    const short* src = att + ((size_t)((pb * 16 + p) * 16 + t0 + tl)) * 256 + seg * 8;
    *(int4*)&A[row * XPAD + seg * 8] = *(const int4*)src;
  }
  __syncthreads();

  f32x4 acc[8][4];
  #pragma unroll
  for (int mt = 0; mt < 8; ++mt)
    #pragma unroll
    for (int n4 = 0; n4 < 4; ++n4) acc[mt][n4] = fzero();

  #pragma unroll
  for (int ks = 0; ks < 8; ++ks) {
    bf16x8 bf[4];
    #pragma unroll
    for (int n4 = 0; n4 < 4; ++n4)
      bf[n4] = *(const bf16x8*)(wpb + (size_t)((wave * 4 + n4) * 16 + li) * 256 + ks * 32 + g * 8);
    #pragma unroll
    for (int mt = 0; mt < 8; ++mt) {
      bf16x8 af = *(const bf16x8*)&A[(mt * 16 + li) * XPAD + ks * 32 + g * 8];
      #pragma unroll
      for (int n4 = 0; n4 < 4; ++n4) acc[mt][n4] = mfma16(af, bf[n4], acc[mt][n4]);
    }
  }

  float* ob = out + (size_t)b * (16 * 256 * 4096) + hw0;
  #pragma unroll
  for (int mt = 0; mt < 8; ++mt)
    #pragma unroll
    for (int n4 = 0; n4 < 4; ++n4) {
      const int t = t0 + mt;
      const int c = (wave * 4 + n4) * 16 + li;
      float4 v;
      v.x = acc[mt][n4][0]; v.y = acc[mt][n4][1];
      v.z = acc[mt][n4][2]; v.w = acc[mt][n4][3];
      *(float4*)(ob + (size_t)(t * 256 + c) * 4096 + g * 4) = v;
    }
}

extern "C" void kernel_launch(void* const* d_in, const int* in_sizes, int n_in,
                              void* d_out, int out_size, void* d_ws, size_t ws_size,
                              hipStream_t stream) {
  const float* x  = (const float*)d_in[0];
  const float* Wq = (const float*)d_in[1];
  const float* Wk = (const float*)d_in[2];
  const float* Wv = (const float*)d_in[3];
  const float* Wp = (const float*)d_in[4];
  float* out = (float*)d_out;

  short* wbf = (short*)d_ws;          // 4 x 65536 bf16 = 512 KB
  short* att = wbf + 4 * 65536;       // attn scratch (bf16), chunked

  wconv_kernel<<<256, 256, 0, stream>>>(Wq, Wk, Wv, Wp, wbf);

  const size_t wsAvail = (ws_size > 524288) ? (ws_size - 524288) : 0;
  const size_t perPix = 16 * 256 * 2;  // 8 KB per pixel each for att, xt, qsg
  int chunk = 64;                      // xt tiles need 64-px groups
  while (chunk < 8192 && (size_t)(chunk * 3) * perPix <= wsAvail) chunk <<= 1;

  short* xtb = att + (size_t)chunk * 4096;   // transposed-x scratch: chunk x 8 KB
  short* qsg = xtb + (size_t)chunk * 4096;   // q_soft scratch:      chunk x 8 KB

  for (int n0 = 0; n0 < 8192; n0 += chunk) {
    xt_kernel<<<(chunk / 64) * 16, 256, 0, stream>>>(x, xtb, n0);
    k1_kernel<<<chunk / 4, 512, 0, stream>>>(xtb, wbf, att, qsg);
    k2_kernel<<<(chunk / 16) * 2, 256, 0, stream>>>(att, wbf + 3 * 65536, out, n0);
  }
}

// Round 10
// 255.788 us; speedup vs baseline: 1.3197x; 1.2745x over previous
//
#include <hip/hip_runtime.h>
#include <hip/hip_bf16.h>

#define DI __device__ __forceinline__

typedef __attribute__((ext_vector_type(8))) short bf16x8;
typedef __attribute__((ext_vector_type(4))) float f32x4;
typedef __attribute__((ext_vector_type(4))) _Float16 f16x4;

constexpr int XPAD = 264;   // k2 A-tile row stride
constexpr float LOG2E = 1.4426950408889634f;

DI float fexp(float x) { return __builtin_amdgcn_exp2f(x * LOG2E); }  // raw v_exp_f32
DI float frcp(float x) { return __builtin_amdgcn_rcpf(x); }           // raw v_rcp_f32

DI short f2bf(float f) {                 // fp32 -> bf16 via HW cvt
  __hip_bfloat16 h = __float2bfloat16(f);
  union { __hip_bfloat16 h; short s; } c; c.h = h; return c.s;
}

DI unsigned pk2(float a, float b) {      // two f32 -> packed bf16x2 (HW cvt_pk)
  union { __hip_bfloat162 h; unsigned u; } c;
  c.h.x = __float2bfloat16(a); c.h.y = __float2bfloat16(b);
  return c.u;
}

DI short f2h(float f) {                  // fp32 -> f16 bits
  _Float16 h = (_Float16)f;
  union { _Float16 h; short s; } c; c.h = h; return c.s;
}

DI f16x4 pkh4(float a, float b, float c, float d) {   // 4 f32 -> f16x4 (cvt_pkrtz)
  auto lo = __builtin_amdgcn_cvt_pkrtz(a, b);         // __fp16 ext_vector(2)
  auto hi = __builtin_amdgcn_cvt_pkrtz(c, d);
  union { struct { decltype(lo) l, h; } p; f16x4 v; } u;
  u.p.l = lo; u.p.h = hi;
  return u.v;
}

DI f16x4 ld4h(const short* p) {          // 4 f16 (8 B)
  union { uint2 u; f16x4 v; } c;
  c.u = *(const uint2*)p;
  return c.v;
}

DI f32x4 mfma16(bf16x8 a, bf16x8 b, f32x4 c) {
  // A: row=l&15, k=(l>>4)*8+j ; B: col=l&15, k=(l>>4)*8+j ; D: col=l&15, row=(l>>4)*4+reg
  return __builtin_amdgcn_mfma_f32_16x16x32_bf16(a, b, c, 0, 0, 0);
}

DI f32x4 mfmah(f16x4 a, f16x4 b, f32x4 c) {
  // 16x16x16 f16: A row=l&15, k=(l>>4)*4+j ; B col=l&15, k=(l>>4)*4+j ; D as above.
  // A/B fragment layout == D layout of the 16x16 family -> GEMM accumulators
  // convert to next-MFMA operands with an own-lane pack (no shfl, no LDS).
  return __builtin_amdgcn_mfma_f32_16x16x16f16(a, b, c, 0, 0, 0);
}

DI f32x4 fzero() { return f32x4{0.f, 0.f, 0.f, 0.f}; }

// Xs swizzled element index: row-major [64][256] bf16, XOR bits 3..5 of the
// element offset with row&7 -> b128 reads across rows hit all 32 banks.
DI int xsw(int row, int e) { return row * 256 + (e ^ ((row & 7) << 3)); }

// ---------------- K0: weights fp32 -> bf16 into ws (Wq pre-scaled) ----------------
__global__ void wconv_kernel(const float* __restrict__ a, const float* __restrict__ b,
                             const float* __restrict__ c, const float* __restrict__ d,
                             short* __restrict__ o) {
  int i = blockIdx.x * 256 + threadIdx.x;
  int mat = i >> 14;                         // block-uniform
  int off = (i & 16383) * 4;
  const float* s = (mat == 0) ? a : (mat == 1) ? b : (mat == 2) ? c : d;
  const float sc = (mat == 0) ? 0.125f : 1.0f;   // fold Ch^-0.5 into Wq
  float4 v = *(const float4*)(s + off);
  uint2 r; r.x = pk2(v.x * sc, v.y * sc); r.y = pk2(v.z * sc, v.w * sc);
  *(uint2*)(o + mat * 65536 + off) = r;
}

// ---------------- K0x: x -> bf16, transposed into k1's EXACT swizzled Xs order ----
// Round-9 rewrite: the old xt burned ~64 scalar ds_write_b16 per thread
// (LDS-instruction-rate bound, ~2x its BW floor).  New scheme, all wide ops:
//  read : register 4x4 transpose (4 strided float4 -> cvt_pk -> 4x 8B LDS st)
//  LDS  : granule-XOR layout, 16B granule g of row px at g ^ ((px>>2)&7)
//         (no padding, 32 KB, everything 16B-aligned, ~2-4-way worst case)
//  write: ds_read_b128 full granules; each wave stores 2 FULL 512B rows per
//         iter (int4), perfectly coalesced regardless of the output swizzle.
__global__ __launch_bounds__(256, 4)
void xt_kernel(const float* __restrict__ x, short* __restrict__ xt, int n0chunk) {
  __shared__ short T[64 * 256];       // 32 KB, granule-XOR layout
  const int tid = threadIdx.x;
  const int gi  = blockIdx.x >> 4;    // 64-px group within chunk
  const int t   = blockIdx.x & 15;
  const int n0g = n0chunk + gi * 64;  // global pixel base (64-aligned)
  const int b   = n0g >> 12;
  const int hw0 = n0g & 4095;
  const float* xb = x + ((size_t)(b * 16 + t) * 256) * 4096 + hw0;

  // ---- read phase: 4x4 register transpose, 8B LDS stores ----
  {
    const int px4 = tid & 15;          // pixel quad 0..15 (px = px4*4 + j)
    const int kk  = px4 & 7;           // T granule key for rows of this quad
    #pragma unroll
    for (int ci = 0; ci < 4; ++ci) {
      const int cq = ci * 16 + (tid >> 4);     // c-quad 0..63 (c = cq*4 + j)
      const float* src = xb + (size_t)(cq * 4) * 4096 + px4 * 4;
      float4 v0 = *(const float4*)(src);
      float4 v1 = *(const float4*)(src + 4096);
      float4 v2 = *(const float4*)(src + 8192);
      float4 v3 = *(const float4*)(src + 12288);
      const int base = ((cq >> 1) ^ kk) * 8 + (cq & 1) * 4;   // shorts, in-row
      uint2 s0; s0.x = pk2(v0.x, v1.x); s0.y = pk2(v2.x, v3.x);
      uint2 s1; s1.x = pk2(v0.y, v1.y); s1.y = pk2(v2.y, v3.y);
      uint2 s2; s2.x = pk2(v0.z, v1.z); s2.y = pk2(v2.z, v3.z);
      uint2 s3; s3.x = pk2(v0.w, v1.w); s3.y = pk2(v2.w, v3.w);
      *(uint2*)&T[(px4 * 4 + 0) * 256 + base] = s0;
      *(uint2*)&T[(px4 * 4 + 1) * 256 + base] = s1;
      *(uint2*)&T[(px4 * 4 + 2) * 256 + base] = s2;
      *(uint2*)&T[(px4 * 4 + 3) * 256 + base] = s3;
    }
  }
  __syncthreads();

  // ---- write phase: b128 granule reads; 2 full 512B rows per wave-inst ----
  {
    const int g0 = tid & 31;           // logical 16B granule 0..31 within row
    #pragma unroll
    for (int rr = 0; rr < 8; ++rr) {
      const int px  = rr * 8 + (tid >> 5);
      const int row = (px & 3) * 16 + t;
      const int kk  = (px >> 2) & 7;
      int4 w = *(const int4*)&T[px * 256 + ((g0 ^ kk) * 8)];
      const size_t obase = ((size_t)(gi * 16 + (px >> 2))) * 16384 + row * 256;
      *(int4*)&xt[obase + ((g0 ^ (row & 7)) * 8)] = w;
    }
  }
}

// ---------------- K1: fused QKV + softmaxes + linear attention ----------------
// One WG = 4 consecutive pixels, 256 threads (4 waves). Each wave = one head.
// (r7 structure, best measured k1: Q-first -> qsg, per-pass accumulators die
// into 16-reg f16 frags, register-kv stage B, fexp/frcp, (256,4), VGPR 64.)
__global__ __launch_bounds__(256, 4)
void k1_kernel(const short* __restrict__ xt, const short* __restrict__ wbf,
               short* __restrict__ att, short* __restrict__ qsg) {
  __shared__ short SMEM[16384];       // 32768 B: Xs only
  short* Xs = SMEM;

  const int tid  = threadIdx.x;
  const int wave = tid >> 6;          // = head
  const int lane = tid & 63;
  const int g    = lane >> 4;
  const int li   = lane & 15;

  // XCD-aware swizzle: consecutive logical bids (adjacent pixels) on same XCD
  int bid = blockIdx.x;
  const int nb = gridDim.x;
  if ((nb & 7) == 0) { const int q = nb >> 3; bid = (bid & 7) * q + (bid >> 3); }

  // ---- Phase 0: async linear copy of the pre-swizzled 32 KB tile ----
  {
    const short* src = xt + (size_t)bid * 16384 + wave * 512 + lane * 8;
    #pragma unroll
    for (int it = 0; it < 8; ++it) {
      __builtin_amdgcn_global_load_lds(
          (const __attribute__((address_space(1))) void*)(src + it * 2048),
          (__attribute__((address_space(3))) void*)(SMEM + it * 2048 + wave * 512),
          16, 0, 0);
    }
  }
  __syncthreads();   // the ONLY barrier (drains vmcnt incl. global_load_lds)

  const short* wq = wbf;
  const short* wk = wbf + 65536;
  const short* wv = wbf + 131072;
  const size_t wrow = (size_t)(wave * 64) * 256;
  // per (px, head) q_soft tile: 16 t x 64 c f16 = 1024 shorts
  short* qsw = qsg + ((size_t)bid * 4 * 4 + wave) * 1024;

  // ---- Pass Q FIRST (all 4 px; scale pre-folded into wq) ----
  {
    f32x4 qacc[4][4];
    #pragma unroll
    for (int p = 0; p < 4; ++p)
      #pragma unroll
      for (int nt = 0; nt < 4; ++nt) qacc[p][nt] = fzero();

    __builtin_amdgcn_s_setprio(1);
    #pragma unroll
    for (int ks = 0; ks < 8; ++ks) {
      bf16x8 qb[4];
      #pragma unroll
      for (int nt = 0; nt < 4; ++nt)
        qb[nt] = *(const bf16x8*)(wq + wrow + (size_t)(nt * 16 + li) * 256 + ks * 32 + g * 8);
      #pragma unroll
      for (int p = 0; p < 4; ++p) {
        bf16x8 af = *(const bf16x8*)&Xs[xsw(p * 16 + li, ks * 32 + g * 8)];
        #pragma unroll
        for (int nt = 0; nt < 4; ++nt)
          qacc[p][nt] = mfma16(af, qb[nt], qacc[p][nt]);
      }
    }
    __builtin_amdgcn_s_setprio(0);

    // Q softmax over c (64 per head), no max-sub -> normalized f16 to qsg
    #pragma unroll
    for (int p = 0; p < 4; ++p) {
      short* qsp = qsw + p * 4096;     // px stride = 4 heads * 1024
      #pragma unroll
      for (int r = 0; r < 4; ++r) {
        float e0 = fexp(qacc[p][0][r]);
        float e1 = fexp(qacc[p][1][r]);
        float e2 = fexp(qacc[p][2][r]);
        float e3 = fexp(qacc[p][3][r]);
        float s = e0 + e1 + e2 + e3;
        s += __shfl_xor(s, 1); s += __shfl_xor(s, 2);
        s += __shfl_xor(s, 4); s += __shfl_xor(s, 8);
        const float inv = frcp(s);
        const int t = g * 4 + r;
        short* dst = qsp + t * 64 + li;
        dst[0]  = f2h(e0 * inv);
        dst[16] = f2h(e1 * inv);
        dst[32] = f2h(e2 * inv);
        dst[48] = f2h(e3 * inv);
      }
    }
  }

  // ---- Pass K (all 4 px) -> t-softmax -> own-lane f16 A-frags ----
  f16x4 akf[4][4];
  {
    f32x4 kacc[4][4];
    #pragma unroll
    for (int p = 0; p < 4; ++p)
      #pragma unroll
      for (int nt = 0; nt < 4; ++nt) kacc[p][nt] = fzero();

    __builtin_amdgcn_s_setprio(1);
    #pragma unroll
    for (int ks = 0; ks < 8; ++ks) {
      bf16x8 kb[4];
      #pragma unroll
      for (int nt = 0; nt < 4; ++nt)
        kb[nt] = *(const bf16x8*)(wk + wrow + (size_t)(nt * 16 + li) * 256 + ks * 32 + g * 8);
      #pragma unroll
      for (int p = 0; p < 4; ++p) {
        bf16x8 af = *(const bf16x8*)&Xs[xsw(p * 16 + li, ks * 32 + g * 8)];
        #pragma unroll
        for (int nt = 0; nt < 4; ++nt)
          kacc[p][nt] = mfma16(af, kb[nt], kacc[p][nt]);
      }
    }
    __builtin_amdgcn_s_setprio(0);

    // softmax over t (4 regs + g-groups), no max-sub (scores ~ N(0,1))
    #pragma unroll
    for (int p = 0; p < 4; ++p)
      #pragma unroll
      for (int nt = 0; nt < 4; ++nt) {
        float e0 = fexp(kacc[p][nt][0]);
        float e1 = fexp(kacc[p][nt][1]);
        float e2 = fexp(kacc[p][nt][2]);
        float e3 = fexp(kacc[p][nt][3]);
        float s = e0 + e1 + e2 + e3;
        s += __shfl_xor(s, 16);
        s += __shfl_xor(s, 32);
        const float inv = frcp(s);
        akf[p][nt] = pkh4(e0 * inv, e1 * inv, e2 * inv, e3 * inv);
      }
  }

  // ---- Pass V (two nt-halves; vacc[4][2] live) -> own-lane f16 B-frags ----
  f16x4 bvf[4][4];
  #pragma unroll
  for (int h = 0; h < 2; ++h) {
    f32x4 vacc[4][2];
    #pragma unroll
    for (int p = 0; p < 4; ++p)
      #pragma unroll
      for (int n2 = 0; n2 < 2; ++n2) vacc[p][n2] = fzero();

    __builtin_amdgcn_s_setprio(1);
    #pragma unroll
    for (int ks = 0; ks < 8; ++ks) {
      bf16x8 vb[2];
      #pragma unroll
      for (int n2 = 0; n2 < 2; ++n2)
        vb[n2] = *(const bf16x8*)(wv + wrow + (size_t)((h * 2 + n2) * 16 + li) * 256 + ks * 32 + g * 8);
      #pragma unroll
      for (int p = 0; p < 4; ++p) {
        bf16x8 af = *(const bf16x8*)&Xs[xsw(p * 16 + li, ks * 32 + g * 8)];
        #pragma unroll
        for (int n2 = 0; n2 < 2; ++n2)
          vacc[p][n2] = mfma16(af, vb[n2], vacc[p][n2]);
      }
    }
    __builtin_amdgcn_s_setprio(0);

    #pragma unroll
    for (int p = 0; p < 4; ++p)
      #pragma unroll
      for (int n2 = 0; n2 < 2; ++n2)
        bvf[p][h * 2 + n2] = pkh4(vacc[p][n2][0], vacc[p][n2][1],
                                  vacc[p][n2][2], vacc[p][n2][3]);
  }

  // ensure this wave's qsg stores are retired before reading them back
  asm volatile("s_waitcnt vmcnt(0)" ::: "memory");

  // ---- Per-pixel stage B: kv (16x16x16 f16) pure-register; out; att store ----
  #pragma unroll
  for (int p = 0; p < 4; ++p) {
    const short* qsp = qsw + p * 4096;
    f32x4 oacc[4];
    #pragma unroll
    for (int nt = 0; nt < 4; ++nt) oacc[nt] = fzero();

    #pragma unroll
    for (int cq = 0; cq < 4; ++cq) {        // c-chunks of 16
      // kv chunk: kva[nt] lane holds kv[c=cq*16+g*4+r][d=nt*16+li]
      f32x4 kva[4];
      #pragma unroll
      for (int nt = 0; nt < 4; ++nt)
        kva[nt] = mfmah(akf[p][cq], bvf[p][nt], fzero());
      // aq: A-frag q_soft[t=li][c=cq*16+g*4+j] from qsg (L2-hot)
      f16x4 aq = ld4h(qsp + li * 64 + cq * 16 + g * 4);
      // kva IS the mfmah B-frag (k=g*4+j, n=li) -> own-lane pack, no transpose
      #pragma unroll
      for (int nt = 0; nt < 4; ++nt) {
        f16x4 kb16 = pkh4(kva[nt][0], kva[nt][1], kva[nt][2], kva[nt][3]);
        oacc[nt] = mfmah(aq, kb16, oacc[nt]);
      }
    }

    const size_t arow = ((size_t)bid * 4 + p) * 16;
    #pragma unroll
    for (int nt = 0; nt < 4; ++nt)
      #pragma unroll
      for (int r = 0; r < 4; ++r)
        att[(arow + g * 4 + r) * 256 + wave * 64 + nt * 16 + li] = f2bf(oacc[nt][r]);
  }
}

// ---------------- K2: out = attn @ Wp^T, transposed coalesced store ----------------
__global__ __launch_bounds__(256, 2)
void k2_kernel(const short* __restrict__ att, const short* __restrict__ wpb,
               float* __restrict__ out, int n0chunk) {
  __shared__ short A[128 * XPAD];
  const int tid = threadIdx.x;
  const int wave = tid >> 6, lane = tid & 63, g = lane >> 4, li = lane & 15;
  const int pb = blockIdx.x >> 1;
  const int t0 = (blockIdx.x & 1) * 8;
  const int n0 = n0chunk + pb * 16;
  const int b = n0 >> 12, hw0 = n0 & 4095;

  for (int idx = tid; idx < 128 * 32; idx += 256) {
    const int row = idx >> 5, seg = idx & 31;
    const int p = row & 15, tl = row >> 4;
    const short* src = att + ((size_t)((pb * 16 + p) * 16 + t0 + tl)) * 256 + seg * 8;
    *(int4*)&A[row * XPAD + seg * 8] = *(const int4*)src;
  }
  __syncthreads();

  f32x4 acc[8][4];
  #pragma unroll
  for (int mt = 0; mt < 8; ++mt)
    #pragma unroll
    for (int n4 = 0; n4 < 4; ++n4) acc[mt][n4] = fzero();

  #pragma unroll
  for (int ks = 0; ks < 8; ++ks) {
    bf16x8 bf[4];
    #pragma unroll
    for (int n4 = 0; n4 < 4; ++n4)
      bf[n4] = *(const bf16x8*)(wpb + (size_t)((wave * 4 + n4) * 16 + li) * 256 + ks * 32 + g * 8);
    #pragma unroll
    for (int mt = 0; mt < 8; ++mt) {
      bf16x8 af = *(const bf16x8*)&A[(mt * 16 + li) * XPAD + ks * 32 + g * 8];
      #pragma unroll
      for (int n4 = 0; n4 < 4; ++n4) acc[mt][n4] = mfma16(af, bf[n4], acc[mt][n4]);
    }
  }

  float* ob = out + (size_t)b * (16 * 256 * 4096) + hw0;
  #pragma unroll
  for (int mt = 0; mt < 8; ++mt)
    #pragma unroll
    for (int n4 = 0; n4 < 4; ++n4) {
      const int t = t0 + mt;
      const int c = (wave * 4 + n4) * 16 + li;
      float4 v;
      v.x = acc[mt][n4][0]; v.y = acc[mt][n4][1];
      v.z = acc[mt][n4][2]; v.w = acc[mt][n4][3];
      *(float4*)(ob + (size_t)(t * 256 + c) * 4096 + g * 4) = v;
    }
}

extern "C" void kernel_launch(void* const* d_in, const int* in_sizes, int n_in,
                              void* d_out, int out_size, void* d_ws, size_t ws_size,
                              hipStream_t stream) {
  const float* x  = (const float*)d_in[0];
  const float* Wq = (const float*)d_in[1];
  const float* Wk = (const float*)d_in[2];
  const float* Wv = (const float*)d_in[3];
  const float* Wp = (const float*)d_in[4];
  float* out = (float*)d_out;

  short* wbf = (short*)d_ws;          // 4 x 65536 bf16 = 512 KB
  short* att = wbf + 4 * 65536;       // attn scratch (bf16), chunked

  wconv_kernel<<<256, 256, 0, stream>>>(Wq, Wk, Wv, Wp, wbf);

  const size_t wsAvail = (ws_size > 524288) ? (ws_size - 524288) : 0;
  const size_t perPix = 16 * 256 * 2;  // 8 KB per pixel each for att, xt, qsg
  int chunk = 64;                      // xt tiles need 64-px groups
  while (chunk < 8192 && (size_t)(chunk * 3) * perPix <= wsAvail) chunk <<= 1;

  short* xtb = att + (size_t)chunk * 4096;   // transposed-x scratch: chunk x 8 KB
  short* qsg = xtb + (size_t)chunk * 4096;   // q_soft scratch:      chunk x 8 KB

  for (int n0 = 0; n0 < 8192; n0 += chunk) {
    xt_kernel<<<(chunk / 64) * 16, 256, 0, stream>>>(x, xtb, n0);
    k1_kernel<<<chunk / 4, 256, 0, stream>>>(xtb, wbf, att, qsg);
    k2_kernel<<<(chunk / 16) * 2, 256, 0, stream>>>(att, wbf + 3 * 65536, out, n0);
  }
}

// Round 11
// 242.370 us; speedup vs baseline: 1.3928x; 1.0554x over previous
//
#include <hip/hip_runtime.h>
#include <hip/hip_bf16.h>

#define DI __device__ __forceinline__

typedef __attribute__((ext_vector_type(8))) short bf16x8;
typedef __attribute__((ext_vector_type(4))) float f32x4;
typedef __attribute__((ext_vector_type(4))) _Float16 f16x4;

constexpr int XPAD = 264;   // k2 A-tile row stride
constexpr float LOG2E = 1.4426950408889634f;

DI float fexp(float x) { return __builtin_amdgcn_exp2f(x * LOG2E); }  // raw v_exp_f32
DI float frcp(float x) { return __builtin_amdgcn_rcpf(x); }           // raw v_rcp_f32

DI short f2bf(float f) {                 // fp32 -> bf16 via HW cvt
  __hip_bfloat16 h = __float2bfloat16(f);
  union { __hip_bfloat16 h; short s; } c; c.h = h; return c.s;
}

DI unsigned pk2(float a, float b) {      // two f32 -> packed bf16x2 (HW cvt_pk)
  union { __hip_bfloat162 h; unsigned u; } c;
  c.h.x = __float2bfloat16(a); c.h.y = __float2bfloat16(b);
  return c.u;
}

DI short f2h(float f) {                  // fp32 -> f16 bits
  _Float16 h = (_Float16)f;
  union { _Float16 h; short s; } c; c.h = h; return c.s;
}

DI f16x4 pkh4(float a, float b, float c, float d) {   // 4 f32 -> f16x4 (cvt_pkrtz)
  auto lo = __builtin_amdgcn_cvt_pkrtz(a, b);         // __fp16 ext_vector(2)
  auto hi = __builtin_amdgcn_cvt_pkrtz(c, d);
  union { struct { decltype(lo) l, h; } p; f16x4 v; } u;
  u.p.l = lo; u.p.h = hi;
  return u.v;
}

DI f16x4 ld4h(const short* p) {          // 4 f16 (8 B)
  union { uint2 u; f16x4 v; } c;
  c.u = *(const uint2*)p;
  return c.v;
}

DI f32x4 mfma16(bf16x8 a, bf16x8 b, f32x4 c) {
  // A: row=l&15, k=(l>>4)*8+j ; B: col=l&15, k=(l>>4)*8+j ; D: col=l&15, row=(l>>4)*4+reg
  return __builtin_amdgcn_mfma_f32_16x16x32_bf16(a, b, c, 0, 0, 0);
}

DI f32x4 mfmah(f16x4 a, f16x4 b, f32x4 c) {
  // 16x16x16 f16: A row=l&15, k=(l>>4)*4+j ; B col=l&15, k=(l>>4)*4+j ; D as above.
  // A/B fragment layout == D layout of the 16x16 family -> GEMM accumulators
  // convert to next-MFMA operands with an own-lane pack (no shfl, no LDS).
  return __builtin_amdgcn_mfma_f32_16x16x16f16(a, b, c, 0, 0, 0);
}

DI f32x4 fzero() { return f32x4{0.f, 0.f, 0.f, 0.f}; }

// Xs swizzled element index: row-major [64][256] bf16, XOR bits 3..5 of the
// element offset with row&7 -> b128 reads across rows hit all 32 banks.
DI int xsw(int row, int e) { return row * 256 + (e ^ ((row & 7) << 3)); }

// ---------------- K0: weights fp32 -> bf16 into ws (Wq pre-scaled) ----------------
__global__ void wconv_kernel(const float* __restrict__ a, const float* __restrict__ b,
                             const float* __restrict__ c, const float* __restrict__ d,
                             short* __restrict__ o) {
  int i = blockIdx.x * 256 + threadIdx.x;
  int mat = i >> 14;                         // block-uniform
  int off = (i & 16383) * 4;
  const float* s = (mat == 0) ? a : (mat == 1) ? b : (mat == 2) ? c : d;
  const float sc = (mat == 0) ? 0.125f : 1.0f;   // fold Ch^-0.5 into Wq
  float4 v = *(const float4*)(s + off);
  uint2 r; r.x = pk2(v.x * sc, v.y * sc); r.y = pk2(v.z * sc, v.w * sc);
  *(uint2*)(o + mat * 65536 + off) = r;
}

// ---------------- K1: fused QKV + softmaxes + linear attention ----------------
// One WG = 4 consecutive pixels, 256 threads (4 waves). Each wave = one head.
// Round-10 post-mortem: total tracks WHOLE-PIPELINE HBM traffic; the xt
// pre-transpose kernel's 134 MB round-trip is a net loss (r5 540MB=242.5 vs
// r7/r10 675MB=252.7/255.8).  This round: r5's verified direct-x staging
// (4x4 float4 register transpose -> swizzled Xs) INSIDE k1, combined with
// r7/r10's verified internals (Q-first -> qsg, fexp/frcp, register-kv stage
// B, per-pass accumulators die into 16-reg f16 frags, (256,4), VGPR 64).
__global__ __launch_bounds__(256, 4)
void k1_kernel(const float* __restrict__ x, const short* __restrict__ wbf,
               short* __restrict__ att, short* __restrict__ qsg, int n0chunk) {
  __shared__ short SMEM[16384];       // 32768 B: Xs only
  short* Xs = SMEM;

  const int tid  = threadIdx.x;
  const int wave = tid >> 6;          // = head
  const int lane = tid & 63;
  const int g    = lane >> 4;
  const int li   = lane & 15;

  // XCD-aware swizzle: consecutive logical bids (adjacent pixels) on same XCD
  int bid = blockIdx.x;
  const int nb = gridDim.x;
  if ((nb & 7) == 0) { const int q = nb >> 3; bid = (bid & 7) * q + (bid >> 3); }

  const int n0  = n0chunk + bid * 4;
  const int b   = n0 >> 12;
  const int hw0 = n0 & 4095;
  const float* xb = x + (size_t)b * (16 * 256 * 4096) + hw0;

  // ---- Phase 0: stage x tile -> Xs bf16 (4x4 block transpose, HW cvt_pk) ----
  {
    const int c4 = lane;                 // 4-channel block 0..63
    #pragma unroll
    for (int it = 0; it < 4; ++it) {
      const int t = it * 4 + wave;
      const float* src = xb + (size_t)(t * 256 + c4 * 4) * 4096;
      float4 v0 = *(const float4*)(src);
      float4 v1 = *(const float4*)(src + 4096);
      float4 v2 = *(const float4*)(src + 8192);
      float4 v3 = *(const float4*)(src + 12288);
      uint2 s0; s0.x = pk2(v0.x, v1.x); s0.y = pk2(v2.x, v3.x);
      uint2 s1; s1.x = pk2(v0.y, v1.y); s1.y = pk2(v2.y, v3.y);
      uint2 s2; s2.x = pk2(v0.z, v1.z); s2.y = pk2(v2.z, v3.z);
      uint2 s3; s3.x = pk2(v0.w, v1.w); s3.y = pk2(v2.w, v3.w);
      *(uint2*)&Xs[xsw(0 * 16 + t, c4 * 4)] = s0;
      *(uint2*)&Xs[xsw(1 * 16 + t, c4 * 4)] = s1;
      *(uint2*)&Xs[xsw(2 * 16 + t, c4 * 4)] = s2;
      *(uint2*)&Xs[xsw(3 * 16 + t, c4 * 4)] = s3;
    }
  }
  __syncthreads();   // the ONLY barrier

  const short* wq = wbf;
  const short* wk = wbf + 65536;
  const short* wv = wbf + 131072;
  const size_t wrow = (size_t)(wave * 64) * 256;
  // per (px, head) q_soft tile: 16 t x 64 c f16 = 1024 shorts
  short* qsw = qsg + ((size_t)bid * 4 * 4 + wave) * 1024;

  // ---- Pass Q FIRST (all 4 px; scale pre-folded into wq) ----
  {
    f32x4 qacc[4][4];
    #pragma unroll
    for (int p = 0; p < 4; ++p)
      #pragma unroll
      for (int nt = 0; nt < 4; ++nt) qacc[p][nt] = fzero();

    __builtin_amdgcn_s_setprio(1);
    #pragma unroll
    for (int ks = 0; ks < 8; ++ks) {
      bf16x8 qb[4];
      #pragma unroll
      for (int nt = 0; nt < 4; ++nt)
        qb[nt] = *(const bf16x8*)(wq + wrow + (size_t)(nt * 16 + li) * 256 + ks * 32 + g * 8);
      #pragma unroll
      for (int p = 0; p < 4; ++p) {
        bf16x8 af = *(const bf16x8*)&Xs[xsw(p * 16 + li, ks * 32 + g * 8)];
        #pragma unroll
        for (int nt = 0; nt < 4; ++nt)
          qacc[p][nt] = mfma16(af, qb[nt], qacc[p][nt]);
      }
    }
    __builtin_amdgcn_s_setprio(0);

    // Q softmax over c (64 per head), no max-sub -> normalized f16 to qsg
    #pragma unroll
    for (int p = 0; p < 4; ++p) {
      short* qsp = qsw + p * 4096;     // px stride = 4 heads * 1024
      #pragma unroll
      for (int r = 0; r < 4; ++r) {
        float e0 = fexp(qacc[p][0][r]);
        float e1 = fexp(qacc[p][1][r]);
        float e2 = fexp(qacc[p][2][r]);
        float e3 = fexp(qacc[p][3][r]);
        float s = e0 + e1 + e2 + e3;
        s += __shfl_xor(s, 1); s += __shfl_xor(s, 2);
        s += __shfl_xor(s, 4); s += __shfl_xor(s, 8);
        const float inv = frcp(s);
        const int t = g * 4 + r;
        short* dst = qsp + t * 64 + li;
        dst[0]  = f2h(e0 * inv);
        dst[16] = f2h(e1 * inv);
        dst[32] = f2h(e2 * inv);
        dst[48] = f2h(e3 * inv);
      }
    }
  }

  // ---- Pass K (all 4 px) -> t-softmax -> own-lane f16 A-frags ----
  f16x4 akf[4][4];
  {
    f32x4 kacc[4][4];
    #pragma unroll
    for (int p = 0; p < 4; ++p)
      #pragma unroll
      for (int nt = 0; nt < 4; ++nt) kacc[p][nt] = fzero();

    __builtin_amdgcn_s_setprio(1);
    #pragma unroll
    for (int ks = 0; ks < 8; ++ks) {
      bf16x8 kb[4];
      #pragma unroll
      for (int nt = 0; nt < 4; ++nt)
        kb[nt] = *(const bf16x8*)(wk + wrow + (size_t)(nt * 16 + li) * 256 + ks * 32 + g * 8);
      #pragma unroll
      for (int p = 0; p < 4; ++p) {
        bf16x8 af = *(const bf16x8*)&Xs[xsw(p * 16 + li, ks * 32 + g * 8)];
        #pragma unroll
        for (int nt = 0; nt < 4; ++nt)
          kacc[p][nt] = mfma16(af, kb[nt], kacc[p][nt]);
      }
    }
    __builtin_amdgcn_s_setprio(0);

    // softmax over t (4 regs + g-groups), no max-sub (scores ~ N(0,1))
    #pragma unroll
    for (int p = 0; p < 4; ++p)
      #pragma unroll
      for (int nt = 0; nt < 4; ++nt) {
        float e0 = fexp(kacc[p][nt][0]);
        float e1 = fexp(kacc[p][nt][1]);
        float e2 = fexp(kacc[p][nt][2]);
        float e3 = fexp(kacc[p][nt][3]);
        float s = e0 + e1 + e2 + e3;
        s += __shfl_xor(s, 16);
        s += __shfl_xor(s, 32);
        const float inv = frcp(s);
        akf[p][nt] = pkh4(e0 * inv, e1 * inv, e2 * inv, e3 * inv);
      }
  }

  // ---- Pass V (two nt-halves; vacc[4][2] live) -> own-lane f16 B-frags ----
  f16x4 bvf[4][4];
  #pragma unroll
  for (int h = 0; h < 2; ++h) {
    f32x4 vacc[4][2];
    #pragma unroll
    for (int p = 0; p < 4; ++p)
      #pragma unroll
      for (int n2 = 0; n2 < 2; ++n2) vacc[p][n2] = fzero();

    __builtin_amdgcn_s_setprio(1);
    #pragma unroll
    for (int ks = 0; ks < 8; ++ks) {
      bf16x8 vb[2];
      #pragma unroll
      for (int n2 = 0; n2 < 2; ++n2)
        vb[n2] = *(const bf16x8*)(wv + wrow + (size_t)((h * 2 + n2) * 16 + li) * 256 + ks * 32 + g * 8);
      #pragma unroll
      for (int p = 0; p < 4; ++p) {
        bf16x8 af = *(const bf16x8*)&Xs[xsw(p * 16 + li, ks * 32 + g * 8)];
        #pragma unroll
        for (int n2 = 0; n2 < 2; ++n2)
          vacc[p][n2] = mfma16(af, vb[n2], vacc[p][n2]);
      }
    }
    __builtin_amdgcn_s_setprio(0);

    #pragma unroll
    for (int p = 0; p < 4; ++p)
      #pragma unroll
      for (int n2 = 0; n2 < 2; ++n2)
        bvf[p][h * 2 + n2] = pkh4(vacc[p][n2][0], vacc[p][n2][1],
                                  vacc[p][n2][2], vacc[p][n2][3]);
  }

  // ensure this wave's qsg stores are retired before reading them back
  asm volatile("s_waitcnt vmcnt(0)" ::: "memory");

  // ---- Per-pixel stage B: kv (16x16x16 f16) pure-register; out; att store ----
  #pragma unroll
  for (int p = 0; p < 4; ++p) {
    const short* qsp = qsw + p * 4096;
    f32x4 oacc[4];
    #pragma unroll
    for (int nt = 0; nt < 4; ++nt) oacc[nt] = fzero();

    #pragma unroll
    for (int cq = 0; cq < 4; ++cq) {        // c-chunks of 16
      // kv chunk: kva[nt] lane holds kv[c=cq*16+g*4+r][d=nt*16+li]
      f32x4 kva[4];
      #pragma unroll
      for (int nt = 0; nt < 4; ++nt)
        kva[nt] = mfmah(akf[p][cq], bvf[p][nt], fzero());
      // aq: A-frag q_soft[t=li][c=cq*16+g*4+j] from qsg (L2-hot)
      f16x4 aq = ld4h(qsp + li * 64 + cq * 16 + g * 4);
      // kva IS the mfmah B-frag (k=g*4+j, n=li) -> own-lane pack, no transpose
      #pragma unroll
      for (int nt = 0; nt < 4; ++nt) {
        f16x4 kb16 = pkh4(kva[nt][0], kva[nt][1], kva[nt][2], kva[nt][3]);
        oacc[nt] = mfmah(aq, kb16, oacc[nt]);
      }
    }

    const size_t arow = ((size_t)bid * 4 + p) * 16;
    #pragma unroll
    for (int nt = 0; nt < 4; ++nt)
      #pragma unroll
      for (int r = 0; r < 4; ++r)
        att[(arow + g * 4 + r) * 256 + wave * 64 + nt * 16 + li] = f2bf(oacc[nt][r]);
  }
}

// ---------------- K2: out = attn @ Wp^T, transposed coalesced store ----------------
__global__ __launch_bounds__(256, 2)
void k2_kernel(const short* __restrict__ att, const short* __restrict__ wpb,
               float* __restrict__ out, int n0chunk) {
  __shared__ short A[128 * XPAD];
  const int tid = threadIdx.x;
  const int wave = tid >> 6, lane = tid & 63, g = lane >> 4, li = lane & 15;
  const int pb = blockIdx.x >> 1;
  const int t0 = (blockIdx.x & 1) * 8;
  const int n0 = n0chunk + pb * 16;
  const int b = n0 >> 12, hw0 = n0 & 4095;

  for (int idx = tid; idx < 128 * 32; idx += 256) {
    const int row = idx >> 5, seg = idx & 31;
    const int p = row & 15, tl = row >> 4;
    const short* src = att + ((size_t)((pb * 16 + p) * 16 + t0 + tl)) * 256 + seg * 8;
    *(int4*)&A[row * XPAD + seg * 8] = *(const int4*)src;
  }
  __syncthreads();

  f32x4 acc[8][4];
  #pragma unroll
  for (int mt = 0; mt < 8; ++mt)
    #pragma unroll
    for (int n4 = 0; n4 < 4; ++n4) acc[mt][n4] = fzero();

  #pragma unroll
  for (int ks = 0; ks < 8; ++ks) {
    bf16x8 bf[4];
    #pragma unroll
    for (int n4 = 0; n4 < 4; ++n4)
      bf[n4] = *(const bf16x8*)(wpb + (size_t)((wave * 4 + n4) * 16 + li) * 256 + ks * 32 + g * 8);
    #pragma unroll
    for (int mt = 0; mt < 8; ++mt) {
      bf16x8 af = *(const bf16x8*)&A[(mt * 16 + li) * XPAD + ks * 32 + g * 8];
      #pragma unroll
      for (int n4 = 0; n4 < 4; ++n4) acc[mt][n4] = mfma16(af, bf[n4], acc[mt][n4]);
    }
  }

  float* ob = out + (size_t)b * (16 * 256 * 4096) + hw0;
  #pragma unroll
  for (int mt = 0; mt < 8; ++mt)
    #pragma unroll
    for (int n4 = 0; n4 < 4; ++n4) {
      const int t = t0 + mt;
      const int c = (wave * 4 + n4) * 16 + li;
      float4 v;
      v.x = acc[mt][n4][0]; v.y = acc[mt][n4][1];
      v.z = acc[mt][n4][2]; v.w = acc[mt][n4][3];
      *(float4*)(ob + (size_t)(t * 256 + c) * 4096 + g * 4) = v;
    }
}

extern "C" void kernel_launch(void* const* d_in, const int* in_sizes, int n_in,
                              void* d_out, int out_size, void* d_ws, size_t ws_size,
                              hipStream_t stream) {
  const float* x  = (const float*)d_in[0];
  const float* Wq = (const float*)d_in[1];
  const float* Wk = (const float*)d_in[2];
  const float* Wv = (const float*)d_in[3];
  const float* Wp = (const float*)d_in[4];
  float* out = (float*)d_out;

  short* wbf = (short*)d_ws;          // 4 x 65536 bf16 = 512 KB
  short* att = wbf + 4 * 65536;       // attn scratch (bf16), chunked

  wconv_kernel<<<256, 256, 0, stream>>>(Wq, Wk, Wv, Wp, wbf);

  const size_t wsAvail = (ws_size > 524288) ? (ws_size - 524288) : 0;
  const size_t perPix = 16 * 256 * 2;  // 8 KB per pixel each for att, qsg
  int chunk = 16;
  while (chunk < 8192 && (size_t)(chunk * 2) * perPix <= wsAvail) chunk <<= 1;

  short* qsg = att + (size_t)chunk * 4096;   // q_soft scratch: chunk x 8 KB

  for (int n0 = 0; n0 < 8192; n0 += chunk) {
    k1_kernel<<<chunk / 4, 256, 0, stream>>>(x, wbf, att, qsg, n0);
    k2_kernel<<<(chunk / 16) * 2, 256, 0, stream>>>(att, wbf + 3 * 65536, out, n0);
  }
}